// Round 6
// baseline (8228.825 us; speedup 1.0000x reference)
//
#include <hip/hip_runtime.h>

#define HID   1024
#define BATCH 256
#define TSEQ  128
#define PRED  96
#define IND   7
#define OUTD  7
#define SK    10   // small input dim: 7 features + 3 time-encode dims

typedef __attribute__((ext_vector_type(8))) _Float16 f16x8;
typedef __attribute__((ext_vector_type(4))) float    f32x4;

#define BM   64
#define BN   64
#define GSTR 68    // gates LDS stride (floats), <=2-way bank aliasing (free)

__device__ __forceinline__ float sigmoidf_fast(float x) {
  return 1.0f / (1.0f + __expf(-x));
}
__device__ __forceinline__ float tanhf_fast(float x) {
  float ax = fabsf(x);
  float e  = __expf(-2.0f * ax);
  float r  = (1.0f - e) / (1.0f + e);
  return copysignf(r, x);
}

template<int AUX>
__device__ __forceinline__ void async_cp16(const void* g, void* l) {
  __builtin_amdgcn_global_load_lds(
      (const __attribute__((address_space(1))) void*)g,
      (__attribute__((address_space(3))) void*)l, 16, 0, AUX);
}

// fine-grained wait + barrier (pipeline)
#define WBAR(N) asm volatile("s_waitcnt vmcnt(" #N ")\n\ts_barrier" ::: "memory")
#define BARO()  asm volatile("s_barrier" ::: "memory")

// ---------------------------------------------------------------------------
// Weight prep: fp16 B [n][k], n = grp*64 + gate*16 + u <-> r = gate*1024+grp*16+u
// ---------------------------------------------------------------------------
__global__ __launch_bounds__(256) void prep_kernel(
    const float* __restrict__ Wih0, const float* __restrict__ Whh0,
    const float* __restrict__ bih0, const float* __restrict__ bhh0,
    const float* __restrict__ Wih1, const float* __restrict__ Whh1,
    const float* __restrict__ bih1, const float* __restrict__ bhh1,
    const float* __restrict__ Wih2, const float* __restrict__ Whh2,
    const float* __restrict__ bih2, const float* __restrict__ bhh2,
    _Float16* __restrict__ B0, _Float16* __restrict__ B1, _Float16* __restrict__ B2,
    float* __restrict__ W0p, float* __restrict__ biasP)
{
  size_t e = (size_t)blockIdx.x * 256 + threadIdx.x;
  const size_t S0 = (size_t)4096 * 1024;
  const size_t S1 = (size_t)4096 * 2048;
  if (e < S0) {
    int n = (int)(e >> 10), k = (int)(e & 1023);
    int nb = n >> 6, gate = (n >> 4) & 3, u = n & 15;
    int r = gate * 1024 + nb * 16 + u;
    B0[e] = (_Float16)Whh0[(size_t)r * 1024 + k];
  } else if (e < S0 + S1) {
    size_t q = e - S0;
    int n = (int)(q >> 11), k = (int)(q & 2047);
    int nb = n >> 6, gate = (n >> 4) & 3, u = n & 15;
    int r = gate * 1024 + nb * 16 + u;
    float v = (k < 1024) ? Wih1[(size_t)r * 1024 + k]
                         : Whh1[(size_t)r * 1024 + (k - 1024)];
    B1[q] = (_Float16)v;
  } else if (e < S0 + 2 * S1) {
    size_t q = e - S0 - S1;
    int n = (int)(q >> 11), k = (int)(q & 2047);
    int nb = n >> 6, gate = (n >> 4) & 3, u = n & 15;
    int r = gate * 1024 + nb * 16 + u;
    float v = (k < 1024) ? Wih2[(size_t)r * 1024 + k]
                         : Whh2[(size_t)r * 1024 + (k - 1024)];
    B2[q] = (_Float16)v;
  } else if (e < S0 + 2 * S1 + 40960) {
    int q = (int)(e - S0 - 2 * S1);
    int n = q / 10, k = q - n * 10;
    int nb = n >> 6, gate = (n >> 4) & 3, u = n & 15;
    int r = gate * 1024 + nb * 16 + u;
    W0p[q] = Wih0[(size_t)r * 10 + k];
  } else if (e < S0 + 2 * S1 + 40960 + 12288) {
    int q = (int)(e - S0 - 2 * S1 - 40960);
    int l = q >> 12, n = q & 4095;
    int nb = n >> 6, gate = (n >> 4) & 3, u = n & 15;
    int r = gate * 1024 + nb * 16 + u;
    const float* bi = (l == 0) ? bih0 : (l == 1) ? bih1 : bih2;
    const float* bh = (l == 0) ? bhh0 : (l == 1) ? bhh1 : bhh2;
    biasP[q] = bi[r] + bh[r];
  }
}

// ---------------------------------------------------------------------------
// Encoder wavefront kernel (unchanged): dispatch d = L0@t=d, L1@d-1, L2@d-2.
// ---------------------------------------------------------------------------
__global__ __launch_bounds__(256) void lstm_wave(
    int d,
    _Float16* __restrict__ h0p0, _Float16* __restrict__ h0p1,
    _Float16* __restrict__ h1p0, _Float16* __restrict__ h1p1,
    _Float16* __restrict__ h2p0, _Float16* __restrict__ h2p1,
    const _Float16* __restrict__ B0g, const _Float16* __restrict__ B1g,
    const _Float16* __restrict__ B2g,
    const float* __restrict__ biasP, const float* __restrict__ W0p,
    float* __restrict__ c0, float* __restrict__ c1, float* __restrict__ c2,
    const float* __restrict__ x, const int* __restrict__ xte,
    const float* __restrict__ e0, const float* __restrict__ e1,
    const float* __restrict__ e2, const float* __restrict__ e3)
{
  __shared__ __align__(16) char smem[32768];
  __shared__ float SmallIn[BM * SK];
  __shared__ float W0s[BN * 11];

  const int layer = blockIdx.y >> 2;
  const int mb = blockIdx.y & 3, nb = blockIdx.x;
  const int t = d - layer;
  if (t < 0 || t >= TSEQ) return;
  const int p = d & 1;

  const _Float16 *A1, *A2; _Float16* ho; const _Float16* Bm;
  const float* bias; float* cst; int Kdim;
  if (layer == 0) {
    A1 = p ? h0p1 : h0p0; A2 = A1;              ho = p ? h0p0 : h0p1;
    Bm = B0g; bias = biasP;        cst = c0; Kdim = 1024;
  } else if (layer == 1) {
    A1 = p ? h0p1 : h0p0; A2 = p ? h1p1 : h1p0; ho = p ? h1p0 : h1p1;
    Bm = B1g; bias = biasP + 4096; cst = c1; Kdim = 2048;
  } else {
    A1 = p ? h1p1 : h1p0; A2 = p ? h2p1 : h2p0; ho = p ? h2p0 : h2p1;
    Bm = B2g; bias = biasP + 8192; cst = c2; Kdim = 2048;
  }
  const int Mbase = mb * BM;
  const int tid = threadIdx.x;

  if (layer == 0 && tid < BM) {
    int Mg = Mbase + tid;
    float v[SK];
    const float* xp = x + ((size_t)Mg * TSEQ + t) * IND;
#pragma unroll
    for (int i = 0; i < IND; ++i) v[i] = xp[i];
    const int* ip = xte + ((size_t)Mg * TSEQ + t) * 4;
    int i0 = ip[0], i1 = ip[1], i2 = ip[2], i3 = ip[3];
#pragma unroll
    for (int dd = 0; dd < 3; ++dd)
      v[IND + dd] = e0[i0 * 3 + dd] + e1[i1 * 3 + dd] + e2[i2 * 3 + dd] + e3[i3 * 3 + dd];
#pragma unroll
    for (int i = 0; i < SK; ++i) SmallIn[tid * SK + i] = v[i];
    const float* wp = W0p + (size_t)(nb * BN + tid) * SK;
#pragma unroll
    for (int i = 0; i < SK; ++i) W0s[tid * 11 + i] = wp[i];
  }

  _Float16* As = (_Float16*)smem;
  _Float16* Bs = (_Float16*)(smem + 16384);

  const int w = tid >> 6, lane = tid & 63;
  const int quad = lane >> 4, l16 = lane & 15;
  const int dr = lane >> 4, ds = lane & 15;

  size_t a_goff[4], b_goff[4];
  int lds_off[4];
#pragma unroll
  for (int i = 0; i < 4; ++i) {
    int lrow = w * 16 + i * 4 + dr;
    int sg = ds ^ (i * 4 + dr);
    a_goff[i] = (size_t)(Mbase + lrow) * (HID * 2) + (size_t)sg * 16;
    b_goff[i] = (size_t)(nb * BN + lrow) * ((size_t)Kdim * 2) + (size_t)sg * 16;
    lds_off[i] = lrow * 256 + ds * 16;
  }

  f32x4 acc[4] = {};

  for (int kk = 0; kk < Kdim; kk += 128) {
    const char* Abase = (kk < 1024)
        ? ((const char*)A1 + (size_t)kk * 2)
        : ((const char*)A2 + (size_t)(kk - 1024) * 2);
    const char* Bbase = (const char*)Bm + (size_t)kk * 2;
#pragma unroll
    for (int i = 0; i < 4; ++i) {
      async_cp16<0>(Abase + a_goff[i], smem + lds_off[i]);
      async_cp16<0>(Bbase + b_goff[i], smem + 16384 + lds_off[i]);
    }
    __syncthreads();
#pragma unroll
    for (int ks = 0; ks < 4; ++ks) {
      int segq = (ks * 4 + quad) ^ l16;
      f16x8 bf = *reinterpret_cast<const f16x8*>(Bs + (w * 16 + l16) * 128 + segq * 8);
#pragma unroll
      for (int mt = 0; mt < 4; ++mt) {
        f16x8 af = *reinterpret_cast<const f16x8*>(As + (mt * 16 + l16) * 128 + segq * 8);
        acc[mt] = __builtin_amdgcn_mfma_f32_16x16x32_f16(af, bf, acc[mt], 0, 0, 0);
      }
    }
    __syncthreads();
  }

  float* Gs = (float*)smem;
#pragma unroll
  for (int mt = 0; mt < 4; ++mt) {
    int row = mt * 16 + quad * 4;
    int col = w * 16 + l16;
#pragma unroll
    for (int r = 0; r < 4; ++r)
      Gs[(row + r) * GSTR + col] = acc[mt][r];
  }
  __syncthreads();

#pragma unroll
  for (int i = 0; i < 4; ++i) {
    int m = (tid >> 4) + i * 16;
    int u = tid & 15;
    float gi = Gs[m * GSTR + u];
    float gf = Gs[m * GSTR + 16 + u];
    float gg = Gs[m * GSTR + 32 + u];
    float go = Gs[m * GSTR + 48 + u];
    int nbase = nb * BN;
    gi += bias[nbase + u];
    gf += bias[nbase + 16 + u];
    gg += bias[nbase + 32 + u];
    go += bias[nbase + 48 + u];
    if (layer == 0) {
#pragma unroll
      for (int k = 0; k < SK; ++k) {
        float sv = SmallIn[m * SK + k];
        gi += sv * W0s[u * 11 + k];
        gf += sv * W0s[(16 + u) * 11 + k];
        gg += sv * W0s[(32 + u) * 11 + k];
        go += sv * W0s[(48 + u) * 11 + k];
      }
    }
    size_t cidx = (size_t)(Mbase + m) * HID + (size_t)nb * 16 + u;
    float cold = cst[cidx];
    float cn = sigmoidf_fast(gf) * cold + sigmoidf_fast(gi) * tanhf_fast(gg);
    float hn = sigmoidf_fast(go) * tanhf_fast(cn);
    cst[cidx] = cn;
    ho[cidx] = (_Float16)hn;
  }
}

// ---------------------------------------------------------------------------
// Decoder v7 helpers.
// gemm_k1024: 64x64 tile, K=1024, chunk=128, ring-2 double buffer (encoder's
// proven staging/consume pattern). acc accumulates on top of caller init.
// ---------------------------------------------------------------------------
__device__ __forceinline__ void gemm_k1024(
    const char* Ab, const char* Bb, size_t bstr,
    char* smem, f32x4 (&acc)[4], int Mbase, int nb, int tid)
{
  const int w = tid >> 6, lane = tid & 63;
  const int quad = lane >> 4, l16 = lane & 15;
  size_t a_src[4], b_src[4];
  int ldst[4];
#pragma unroll
  for (int i = 0; i < 4; ++i) {
    int lrow = w * 16 + i * 4 + quad;
    int sg = l16 ^ (i * 4 + quad);
    a_src[i] = (size_t)(Mbase + lrow) * 2048 + (size_t)sg * 16;
    b_src[i] = (size_t)(nb * 64 + lrow) * bstr + (size_t)sg * 16;
    ldst[i] = lrow * 256 + l16 * 16;
  }
#define GISSUE(c) do { \
    char* L_ = smem + ((c) & 1) * 32768; \
    const char* Ab_ = Ab + (size_t)(c) * 256; \
    const char* Bb_ = Bb + (size_t)(c) * 256; \
    _Pragma("unroll") \
    for (int i_ = 0; i_ < 4; ++i_) { \
      async_cp16<0>(Ab_ + a_src[i_], L_ + ldst[i_]); \
      async_cp16<0>(Bb_ + b_src[i_], L_ + 16384 + ldst[i_]); \
    } } while (0)
  GISSUE(0);
#pragma unroll
  for (int c = 0; c < 8; ++c) {
    if (c + 1 < 8) { GISSUE(c + 1); WBAR(8); }
    else           { WBAR(0); }
    const _Float16* As = (const _Float16*)(smem + (c & 1) * 32768);
    const _Float16* Bs = As + 8192;
#pragma unroll
    for (int ks = 0; ks < 4; ++ks) {
      int sq = (ks * 4 + quad) ^ l16;
      f16x8 bf = *reinterpret_cast<const f16x8*>(Bs + (w * 16 + l16) * 128 + sq * 8);
#pragma unroll
      for (int mt = 0; mt < 4; ++mt) {
        f16x8 af = *reinterpret_cast<const f16x8*>(As + (mt * 16 + l16) * 128 + sq * 8);
        acc[mt] = __builtin_amdgcn_mfma_f32_16x16x32_f16(af, bf, acc[mt], 0, 0, 0);
      }
    }
    BARO();   // ring recycle guard
  }
#undef GISSUE
}

// Full epilogue: Gs transpose + bias + pointwise + h/c stores.
// MODE 1: +SmallIn (L0); MODE 0: plain (L1); MODE 2: +fused fc (L2).
template<int MODE>
__device__ __forceinline__ void pointwise(
    f32x4 (&acc)[4], float* Gs, const float* SmallIn, const float* W0s,
    const float* biasL, float* cst, _Float16* ho,
    float* out, const float* fcW, const float* fcb,
    int s, int Mbase, int nb, int tid)
{
  const int w = tid >> 6, lane = tid & 63;
  const int quad = lane >> 4, l16 = lane & 15;
#pragma unroll
  for (int mt = 0; mt < 4; ++mt) {
    int row = mt * 16 + quad * 4;
    int col = w * 16 + l16;
#pragma unroll
    for (int r = 0; r < 4; ++r)
      Gs[(row + r) * GSTR + col] = acc[mt][r];
  }
  __syncthreads();
  const int u = tid & 15;
#pragma unroll
  for (int i = 0; i < 4; ++i) {
    int m = (tid >> 4) + i * 16;
    int nbase = nb * 64;
    float gi = Gs[m * GSTR + u]      + biasL[nbase + u];
    float gf = Gs[m * GSTR + 16 + u] + biasL[nbase + 16 + u];
    float gg = Gs[m * GSTR + 32 + u] + biasL[nbase + 32 + u];
    float go = Gs[m * GSTR + 48 + u] + biasL[nbase + 48 + u];
    if (MODE == 1) {
#pragma unroll
      for (int k = 0; k < SK; ++k) {
        float sv = SmallIn[m * SK + k];
        gi += sv * W0s[u * 11 + k];
        gf += sv * W0s[(16 + u) * 11 + k];
        gg += sv * W0s[(32 + u) * 11 + k];
        go += sv * W0s[(48 + u) * 11 + k];
      }
    }
    size_t cidx = (size_t)(Mbase + m) * HID + (size_t)nb * 16 + u;
    float cold = cst[cidx];
    float cn = sigmoidf_fast(gf) * cold + sigmoidf_fast(gi) * tanhf_fast(gg);
    float hn = sigmoidf_fast(go) * tanhf_fast(cn);
    cst[cidx] = cn;
    ho[cidx] = (_Float16)hn;
    if (MODE == 2) {
#pragma unroll
      for (int o = 0; o < OUTD; ++o) {
        float r = hn * fcW[(size_t)o * HID + nb * 16 + u];
        r += __shfl_xor(r, 1, 16);
        r += __shfl_xor(r, 2, 16);
        r += __shfl_xor(r, 4, 16);
        r += __shfl_xor(r, 8, 16);
        if (u == 0)
          atomicAdd(&out[(size_t)(Mbase + m) * (PRED * OUTD) + (s + 1) * OUTD + o],
                    r + ((nb == 0) ? fcb[o] : 0.0f));
      }
    }
  }
}

// ---------------------------------------------------------------------------
// Decoder v7: two-task dispatches, software-pipelined across dispatches via
// gate-partial blobs (raw acc layout: reader thread == writer thread).
//  PH=0 (DA): taskA L0-epi@s  (gp0 + y@s -> h0,c0)  | taskB L1-high@s (A=h1 -> gp1)
//  PH=1 (DB): taskA L1-low@s  (gp1 + A=h0 -> h1,c1) | taskB L2-high@s (A=h2 -> gp2)
//  PH=2 (DC): taskA L2-low@s  (gp2 + A=h1 -> h2,c2,fc->y@s+1)
//             | taskB L0-full@s+1 (A=h0 -> gp0; skipped at s=PRED-2)
//  PH=3 (prologue, grid (64,4)): L0-full@0 (A=h0enc -> gp0)
// All plain cached ops; coherence = kernel boundaries (v6-proven). All h/gp
// buffers single-buffered: every overwrite is >=1 dispatch after last read.
// ---------------------------------------------------------------------------
template<int PH>
__global__ __launch_bounds__(256, 2) void dec_duo(
    _Float16* __restrict__ h0, _Float16* __restrict__ h1, _Float16* __restrict__ h2,
    const _Float16* __restrict__ B0g, const _Float16* __restrict__ B1g,
    const _Float16* __restrict__ B2g,
    const float* __restrict__ biasP, const float* __restrict__ W0p,
    float* __restrict__ c0, float* __restrict__ c1, float* __restrict__ c2,
    float* __restrict__ out, const int* __restrict__ yte,
    const float* __restrict__ e0, const float* __restrict__ e1,
    const float* __restrict__ e2, const float* __restrict__ e3,
    const float* __restrict__ fcW, const float* __restrict__ fcb,
    float* __restrict__ gp0, float* __restrict__ gp1, float* __restrict__ gp2,
    int s)
{
  __shared__ __align__(16) char smem[65536];   // ring-2 x 32KB; Gs aliases [0,17.4KB)
  __shared__ float SmallIn[64 * SK];
  __shared__ float W0s[64 * 11];

  const int tid = threadIdx.x;
  const int nb = blockIdx.x;
  const int task = (PH == 3) ? 1 : ((int)blockIdx.y >> 2);
  const int mb   = (PH == 3) ? (int)blockIdx.y : ((int)blockIdx.y & 3);
  const int Mbase = mb * 64;
  float* Gs = (float*)smem;
  f32x4 acc[4] = {};

  // blob slot for this (mb, nb, tid): 16 floats
  const size_t bidx = ((size_t)(mb * 64 + nb) * 256 + tid) * 16;

  if (PH == 0) {
    if (task == 0) {
      // ---- L0-epi@s: gates = gp0 + bias + SmallIn; -> h0, c0 ----
      if (tid < 64) {
        int Mg = Mbase + tid;
        float v[SK];
        const float* yp = out + (size_t)Mg * (PRED * OUTD) + s * OUTD;
#pragma unroll
        for (int i = 0; i < OUTD; ++i) v[i] = yp[i];
        const int* ip = yte + ((size_t)Mg * PRED + s) * 4;
        int i0 = ip[0], i1 = ip[1], i2 = ip[2], i3 = ip[3];
#pragma unroll
        for (int dd = 0; dd < 3; ++dd)
          v[IND + dd] = e0[i0 * 3 + dd] + e1[i1 * 3 + dd]
                      + e2[i2 * 3 + dd] + e3[i3 * 3 + dd];
#pragma unroll
        for (int i = 0; i < SK; ++i) SmallIn[tid * SK + i] = v[i];
        const float* wp = W0p + (size_t)(nb * 64 + tid) * SK;
#pragma unroll
        for (int i = 0; i < SK; ++i) W0s[tid * 11 + i] = wp[i];
      }
#pragma unroll
      for (int mt = 0; mt < 4; ++mt)
        acc[mt] = *reinterpret_cast<const f32x4*>(gp0 + bidx + mt * 4);
      __syncthreads();   // SmallIn/W0s ready (Gs writes follow inside pointwise)
      pointwise<1>(acc, Gs, SmallIn, W0s, biasP, c0, h0,
                   out, fcW, fcb, s, Mbase, nb, tid);
    } else {
      // ---- L1-high@s: A = h1@s-1, B = B1 cols[1024:2048) -> gp1 ----
      gemm_k1024((const char*)h1, (const char*)B1g + 2048, 4096,
                 smem, acc, Mbase, nb, tid);
#pragma unroll
      for (int mt = 0; mt < 4; ++mt)
        *reinterpret_cast<f32x4*>(gp1 + bidx + mt * 4) = acc[mt];
    }
  } else if (PH == 1) {
    if (task == 0) {
      // ---- L1-low@s: acc = gp1; A = h0@s, B = B1 cols[0:1024) -> h1, c1 ----
#pragma unroll
      for (int mt = 0; mt < 4; ++mt)
        acc[mt] = *reinterpret_cast<const f32x4*>(gp1 + bidx + mt * 4);
      gemm_k1024((const char*)h0, (const char*)B1g, 4096,
                 smem, acc, Mbase, nb, tid);
      pointwise<0>(acc, Gs, SmallIn, W0s, biasP + 4096, c1, h1,
                   out, fcW, fcb, s, Mbase, nb, tid);
    } else {
      // ---- L2-high@s: A = h2@s-1, B = B2 cols[1024:2048) -> gp2 ----
      gemm_k1024((const char*)h2, (const char*)B2g + 2048, 4096,
                 smem, acc, Mbase, nb, tid);
#pragma unroll
      for (int mt = 0; mt < 4; ++mt)
        *reinterpret_cast<f32x4*>(gp2 + bidx + mt * 4) = acc[mt];
    }
  } else if (PH == 2) {
    if (task == 0) {
      // ---- L2-low@s: acc = gp2; A = h1@s, B = B2 cols[0:1024) ----
      //      -> h2, c2, fused fc -> y@s+1 ----
#pragma unroll
      for (int mt = 0; mt < 4; ++mt)
        acc[mt] = *reinterpret_cast<const f32x4*>(gp2 + bidx + mt * 4);
      gemm_k1024((const char*)h1, (const char*)B2g, 4096,
                 smem, acc, Mbase, nb, tid);
      pointwise<2>(acc, Gs, SmallIn, W0s, biasP + 8192, c2, h2,
                   out, fcW, fcb, s, Mbase, nb, tid);
    } else {
      // ---- L0-full@s+1: A = h0@s, B = B0 (K=1024) -> gp0 ----
      if (s >= PRED - 2) return;   // no step s+1 GEMM needed after last step
      gemm_k1024((const char*)h0, (const char*)B0g, 2048,
                 smem, acc, Mbase, nb, tid);
#pragma unroll
      for (int mt = 0; mt < 4; ++mt)
        *reinterpret_cast<f32x4*>(gp0 + bidx + mt * 4) = acc[mt];
    }
  } else {
    // ---- PH=3 prologue: L0-full@0: A = h0enc -> gp0 ----
    gemm_k1024((const char*)h0, (const char*)B0g, 2048,
               smem, acc, Mbase, nb, tid);
#pragma unroll
    for (int mt = 0; mt < 4; ++mt)
      *reinterpret_cast<f32x4*>(gp0 + bidx + mt * 4) = acc[mt];
  }
}

// ---------------------------------------------------------------------------
// Standalone FC head for y0 only: y = h2 @ fcW^T + fcb -> out[:,0,:].
// ---------------------------------------------------------------------------
__global__ __launch_bounds__(256) void fc_kernel(
    const _Float16* __restrict__ h2, const float* __restrict__ fcW,
    const float* __restrict__ fcb, float* __restrict__ out)
{
  int wv = threadIdx.x >> 6, lane = threadIdx.x & 63;
  int row = blockIdx.x * 4 + wv;
  const _Float16* hp = h2 + (size_t)row * HID + lane * 16;
  float hv[16];
#pragma unroll
  for (int i = 0; i < 16; ++i) hv[i] = (float)hp[i];
  float acc[OUTD];
#pragma unroll
  for (int o = 0; o < OUTD; ++o) {
    const float* wp = fcW + (size_t)o * HID + lane * 16;
    float a = 0.f;
#pragma unroll
    for (int i = 0; i < 16; ++i) a += hv[i] * wp[i];
    acc[o] = a;
  }
#pragma unroll
  for (int o = 0; o < OUTD; ++o)
#pragma unroll
    for (int off = 32; off >= 1; off >>= 1)
      acc[o] += __shfl_xor(acc[o], off, 64);
  if (lane == 0) {
#pragma unroll
    for (int o = 0; o < OUTD; ++o)
      out[(size_t)row * (PRED * OUTD) + o] = acc[o] + fcb[o];
  }
}

// ---------------------------------------------------------------------------
// Workspace layout (bytes):
//   B0 @0 (8 MB) | B1 @8388608 (16 MB) | B2 @25165824 (16 MB)
//   W0p @41943040 | biasP @42106880
//   h par0 @42156032 (1.5 MB) + c @43728896 (3 MB)  } one memset
//   h par1 @46874624 (1.5 MB)                        } second memset
//   gp0 @48447488 (4 MB) | gp1 @52641792 (4 MB) | gp2 @56836096 (4 MB)
// ---------------------------------------------------------------------------
extern "C" void kernel_launch(void* const* d_in, const int* in_sizes, int n_in,
                              void* d_out, int out_size, void* d_ws, size_t ws_size,
                              hipStream_t stream) {
  const float* x   = (const float*)d_in[0];
  const int*   xte = (const int*)d_in[2];
  const int*   yte = (const int*)d_in[3];
  const float* e0  = (const float*)d_in[4];
  const float* e1  = (const float*)d_in[5];
  const float* e2  = (const float*)d_in[6];
  const float* e3  = (const float*)d_in[7];
  const float* Wih0 = (const float*)d_in[8];
  const float* Whh0 = (const float*)d_in[9];
  const float* bih0 = (const float*)d_in[10];
  const float* bhh0 = (const float*)d_in[11];
  const float* Wih1 = (const float*)d_in[12];
  const float* Whh1 = (const float*)d_in[13];
  const float* bih1 = (const float*)d_in[14];
  const float* bhh1 = (const float*)d_in[15];
  const float* Wih2 = (const float*)d_in[16];
  const float* Whh2 = (const float*)d_in[17];
  const float* bih2 = (const float*)d_in[18];
  const float* bhh2 = (const float*)d_in[19];
  const float* fcW = (const float*)d_in[20];
  const float* fcb = (const float*)d_in[21];
  float* out = (float*)d_out;

  char* ws = (char*)d_ws;
  _Float16* B0   = (_Float16*)(ws);
  _Float16* B1   = (_Float16*)(ws + 8388608);
  _Float16* B2   = (_Float16*)(ws + 25165824);
  float*    W0p  = (float*)(ws + 41943040);
  float*    biasP= (float*)(ws + 42106880);
  char*     hp0  = ws + 42156032;
  float*    cbuf = (float*)(ws + 43728896);
  char*     hp1  = ws + 46874624;
  float*    gp0  = (float*)(ws + 48447488);
  float*    gp1  = (float*)(ws + 52641792);
  float*    gp2  = (float*)(ws + 56836096);

  hipMemsetAsync(out, 0, (size_t)out_size * 4, stream);
  hipMemsetAsync(hp0, 0, 4718592, stream);
  hipMemsetAsync(hp1, 0, 1572864, stream);

  prep_kernel<<<82128, 256, 0, stream>>>(Wih0, Whh0, bih0, bhh0,
                                         Wih1, Whh1, bih1, bhh1,
                                         Wih2, Whh2, bih2, bhh2,
                                         B0, B1, B2, W0p, biasP);

  auto hb = [&](int l, int par) -> _Float16* {
    return (_Float16*)((par ? hp1 : hp0) + (size_t)l * 524288);
  };
  float* cl[3] = {cbuf, cbuf + 262144, cbuf + 524288};

  // encoder: wavefront over (layer, t) diagonals
  for (int d = 0; d < TSEQ + 2; ++d) {
    lstm_wave<<<dim3(64, 12), 256, 0, stream>>>(
        d, hb(0,0), hb(0,1), hb(1,0), hb(1,1), hb(2,0), hb(2,1),
        B0, B1, B2, biasP, W0p, cl[0], cl[1], cl[2],
        x, xte, e0, e1, e2, e3);
  }

  // handoff: h0@127 -> par0, h1@127 -> par1, h2@127 -> par0 (single-buffered
  // in the decoder: reader-before-writer ordering verified per buffer)
  _Float16* h0 = hb(0, 0);
  _Float16* h1 = hb(1, 1);
  _Float16* h2 = hb(2, 0);

  fc_kernel<<<64, 256, 0, stream>>>(h2, fcW, fcb, out);   // y0

  // prologue: gp0@0 from encoder h0
  dec_duo<3><<<dim3(64, 4), 256, 0, stream>>>(
      h0, h1, h2, B0, B1, B2, biasP, W0p, cl[0], cl[1], cl[2],
      out, yte, e0, e1, e2, e3, fcW, fcb, gp0, gp1, gp2, 0);

  // 95 steps x 3 two-task dispatches
  for (int s = 0; s < PRED - 1; ++s) {
    dec_duo<0><<<dim3(64, 8), 256, 0, stream>>>(
        h0, h1, h2, B0, B1, B2, biasP, W0p, cl[0], cl[1], cl[2],
        out, yte, e0, e1, e2, e3, fcW, fcb, gp0, gp1, gp2, s);
    dec_duo<1><<<dim3(64, 8), 256, 0, stream>>>(
        h0, h1, h2, B0, B1, B2, biasP, W0p, cl[0], cl[1], cl[2],
        out, yte, e0, e1, e2, e3, fcW, fcb, gp0, gp1, gp2, s);
    dec_duo<2><<<dim3(64, 8), 256, 0, stream>>>(
        h0, h1, h2, B0, B1, B2, biasP, W0p, cl[0], cl[1], cl[2],
        out, yte, e0, e1, e2, e3, fcW, fcb, gp0, gp1, gp2, s);
  }
}